// Round 1
// baseline (3057.557 us; speedup 1.0000x reference)
//
#include <hip/hip_runtime.h>
#include <hip/hip_bf16.h>
#include <math.h>

#define HIDDEN 1024
#define BATCH 32
#define SRC_LEN 2048
#define NROWS (BATCH * SRC_LEN)   // 65536
#define NEG_BIG -10000000000.0f

// ---------------------------------------------------------------------------
// Kernel 1: dec_proj[b][k] = sum_h dh[b][h] * W_dec[h][k] + bias[k]
// grid (4 ktiles, 8 bgroups), block 256. Each thread: one k, 4 batches.
// ---------------------------------------------------------------------------
__global__ __launch_bounds__(256) void k_dec_proj(
    const float* __restrict__ dh, const float* __restrict__ W,
    const float* __restrict__ bias, float* __restrict__ out) {
  int k = blockIdx.x * 256 + threadIdx.x;
  int b0 = blockIdx.y * 4;
  __shared__ float dh_s[4][64];
  float acc[4] = {0.f, 0.f, 0.f, 0.f};
  for (int h0 = 0; h0 < HIDDEN; h0 += 64) {
    __syncthreads();
    {
      int b = threadIdx.x >> 6, hh = threadIdx.x & 63;
      dh_s[b][hh] = dh[(b0 + b) * HIDDEN + h0 + hh];
    }
    __syncthreads();
#pragma unroll 16
    for (int hh = 0; hh < 64; ++hh) {
      float w = W[(h0 + hh) * HIDDEN + k];
#pragma unroll
      for (int b = 0; b < 4; ++b) acc[b] += dh_s[b][hh] * w;
    }
  }
  float bk = bias[k];
#pragma unroll
  for (int b = 0; b < 4; ++b) out[(b0 + b) * HIDDEN + k] = acc[b] + bk;
}

// ---------------------------------------------------------------------------
// Kernel 2 (dominant): fused  logits[row] = sum_k tanh(dec_proj[b][k] +
//   sum_h enc[row][h]*W_enc[h][k]) * v_w[k]
// grid 4096 (16 rows/block), block 256 = 4 waves.
// Thread (ty=wave, tx=lane): rows ty*4+{0..3}, cols tx + 64*{0..15}.
// W_enc panel (8 x 1024, 32KB) + A panel (16 x 8) staged in LDS per h-tile.
// ---------------------------------------------------------------------------
__global__ __launch_bounds__(256) void k_energy(
    const float* __restrict__ enc, const float* __restrict__ Wenc,
    const float* __restrict__ dec_proj, const float* __restrict__ v_w,
    float* __restrict__ logits) {
  __shared__ float B_s[8][HIDDEN];   // 32 KB
  __shared__ float A_s[16][8];

  const int tid = threadIdx.x;
  const int tx = tid & 63;   // lane
  const int ty = tid >> 6;   // wave 0..3
  const int row0 = blockIdx.x * 16;
  const int b = row0 >> 11;  // row0 / SRC_LEN

  float acc[4][16];
#pragma unroll
  for (int i = 0; i < 4; ++i)
#pragma unroll
    for (int j = 0; j < 16; ++j) acc[i][j] = 0.f;

  const float4* enc4 = (const float4*)enc;
  const float4* W4 = (const float4*)Wenc;
  float4* B4 = (float4*)B_s;
  float4* A4 = (float4*)A_s;

  for (int h0 = 0; h0 < HIDDEN; h0 += 8) {
    __syncthreads();
    // stage B: 8 rows x 1024 cols = 2048 float4, 8 per thread (coalesced)
#pragma unroll
    for (int t = 0; t < 8; ++t) {
      int idx = tid + t * 256;           // 0..2047
      int hh = idx >> 8, k4 = idx & 255;
      B4[hh * 256 + k4] = W4[(h0 + hh) * 256 + k4];
    }
    // stage A: 16 rows x 8 cols = 32 float4
    if (tid < 32) {
      int r = tid >> 1, c = tid & 1;
      A4[r * 2 + c] = enc4[(row0 + r) * 256 + (h0 >> 2) + c];
    }
    __syncthreads();
#pragma unroll
    for (int hh = 0; hh < 8; ++hh) {
      float a[4], bb[16];
#pragma unroll
      for (int i = 0; i < 4; ++i) a[i] = A_s[ty * 4 + i][hh];  // broadcast
#pragma unroll
      for (int j = 0; j < 16; ++j) bb[j] = B_s[hh][tx + 64 * j];  // 2-way, free
#pragma unroll
      for (int i = 0; i < 4; ++i)
#pragma unroll
        for (int j = 0; j < 16; ++j) acc[i][j] += a[i] * bb[j];
    }
  }

  // epilogue: tanh + dot with v_w, wave-reduce over the 64 lanes (k dim)
  float dec[16], vr[16];
#pragma unroll
  for (int j = 0; j < 16; ++j) {
    int k = tx + 64 * j;
    dec[j] = dec_proj[b * HIDDEN + k];
    vr[j] = v_w[k];
  }
#pragma unroll
  for (int i = 0; i < 4; ++i) {
    float s = 0.f;
#pragma unroll
    for (int j = 0; j < 16; ++j) s += tanhf(dec[j] + acc[i][j]) * vr[j];
#pragma unroll
    for (int off = 32; off; off >>= 1) s += __shfl_xor(s, off);
    if (tx == 0) logits[row0 + ty * 4 + i] = s;
  }
}

// ---------------------------------------------------------------------------
// Kernel 3: masked softmax over s per batch. grid 32, block 256.
// ---------------------------------------------------------------------------
__global__ __launch_bounds__(256) void k_softmax(
    const float* __restrict__ logits, const int* __restrict__ mask,
    float* __restrict__ out_w) {
  int b = blockIdx.x, tid = threadIdx.x;
  __shared__ float red[4], red2[4];
  float l[8];
  float m = -INFINITY;
#pragma unroll
  for (int j = 0; j < 8; ++j) {
    int s = tid + 256 * j;
    float x = logits[b * SRC_LEN + s];
    l[j] = (mask[b * SRC_LEN + s] == 0) ? NEG_BIG : x;
    m = fmaxf(m, l[j]);
  }
#pragma unroll
  for (int off = 32; off; off >>= 1) m = fmaxf(m, __shfl_xor(m, off));
  if ((tid & 63) == 0) red[tid >> 6] = m;
  __syncthreads();
  m = fmaxf(fmaxf(red[0], red[1]), fmaxf(red[2], red[3]));
  float sum = 0.f;
#pragma unroll
  for (int j = 0; j < 8; ++j) {
    l[j] = expf(l[j] - m);
    sum += l[j];
  }
#pragma unroll
  for (int off = 32; off; off >>= 1) sum += __shfl_xor(sum, off);
  if ((tid & 63) == 0) red2[tid >> 6] = sum;
  __syncthreads();
  sum = red2[0] + red2[1] + red2[2] + red2[3];
  float inv = 1.f / sum;
#pragma unroll
  for (int j = 0; j < 8; ++j) out_w[b * SRC_LEN + tid + 256 * j] = l[j] * inv;
}

// ---------------------------------------------------------------------------
// Kernel 4: context partials. grid (32, 16), block 256 (each thread: float4 of h).
// partial[b][sg][h] = sum_{s in sg chunk of 128} w[b][s] * enc[b][s][h]
// ---------------------------------------------------------------------------
__global__ __launch_bounds__(256) void k_ctx_partial(
    const float* __restrict__ w, const float* __restrict__ enc,
    float* __restrict__ part) {
  int b = blockIdx.x, sg = blockIdx.y, tid = threadIdx.x;
  const float4* enc4 = (const float4*)enc;
  float4 acc = {0.f, 0.f, 0.f, 0.f};
  int s0 = sg * 128;
#pragma unroll 4
  for (int s = 0; s < 128; ++s) {
    float ws = w[b * SRC_LEN + s0 + s];
    float4 e = enc4[(b * SRC_LEN + s0 + s) * 256 + tid];
    acc.x += ws * e.x;
    acc.y += ws * e.y;
    acc.z += ws * e.z;
    acc.w += ws * e.w;
  }
  ((float4*)part)[(b * 16 + sg) * 256 + tid] = acc;
}

// ---------------------------------------------------------------------------
// Kernel 5: reduce the 16 partials -> context. grid 32, block 256.
// ---------------------------------------------------------------------------
__global__ __launch_bounds__(256) void k_ctx_reduce(
    const float* __restrict__ part, float* __restrict__ ctx) {
  int b = blockIdx.x, tid = threadIdx.x;
  float4 acc = {0.f, 0.f, 0.f, 0.f};
#pragma unroll
  for (int sg = 0; sg < 16; ++sg) {
    float4 p = ((const float4*)part)[(b * 16 + sg) * 256 + tid];
    acc.x += p.x;
    acc.y += p.y;
    acc.z += p.z;
    acc.w += p.w;
  }
  ((float4*)ctx)[b * 256 + tid] = acc;
}

// ---------------------------------------------------------------------------
extern "C" void kernel_launch(void* const* d_in, const int* in_sizes, int n_in,
                              void* d_out, int out_size, void* d_ws, size_t ws_size,
                              hipStream_t stream) {
  const float* dh = (const float*)d_in[0];        // [32][1024]
  const float* enc = (const float*)d_in[1];       // [32][2048][1024]
  const int* mask = (const int*)d_in[2];          // [32][2048]
  const float* attn_W = (const float*)d_in[3];    // [2048][1024]
  const float* attn_b = (const float*)d_in[4];    // [1024]
  const float* v_w = (const float*)d_in[5];       // [1024]

  const float* W_dec = attn_W;                    // rows 0..1023
  const float* W_enc = attn_W + HIDDEN * HIDDEN;  // rows 1024..2047

  float* out_w = (float*)d_out;                   // [32][2048] attention_weights
  float* out_ctx = (float*)d_out + NROWS;         // [32][1024] context

  float* ws = (float*)d_ws;
  float* logits = ws;                             // 65536
  float* dec_proj = ws + NROWS;                   // 32768
  float* part = ws + NROWS + BATCH * HIDDEN;      // 32*16*1024 = 524288

  k_dec_proj<<<dim3(4, 8), 256, 0, stream>>>(dh, W_dec, attn_b, dec_proj);
  k_energy<<<dim3(NROWS / 16), 256, 0, stream>>>(enc, W_enc, dec_proj, v_w, logits);
  k_softmax<<<dim3(BATCH), 256, 0, stream>>>(logits, mask, out_w);
  k_ctx_partial<<<dim3(BATCH, 16), 256, 0, stream>>>(out_w, enc, part);
  k_ctx_reduce<<<dim3(BATCH), 256, 0, stream>>>(part, out_ctx);
}

// Round 2
// 722.460 us; speedup vs baseline: 4.2321x; 4.2321x over previous
//
#include <hip/hip_runtime.h>
#include <hip/hip_bf16.h>
#include <math.h>

#define HIDDEN 1024
#define BATCH 32
#define SRC_LEN 2048
#define NROWS (BATCH * SRC_LEN)   // 65536
#define NEG_BIG -10000000000.0f

typedef __attribute__((ext_vector_type(8))) short bf16x8;
typedef __attribute__((ext_vector_type(4))) float f32x4;

static __device__ __forceinline__ unsigned short f2bf(float f) {
  unsigned u = __float_as_uint(f);
  u = u + 0x7fffu + ((u >> 16) & 1u);
  return (unsigned short)(u >> 16);
}
static __device__ __forceinline__ unsigned pack2(float a, float b) {
  return (unsigned)f2bf(a) | ((unsigned)f2bf(b) << 16);
}

// ---------------------------------------------------------------------------
// Kernel 0: WT[n][h] = bf16(W_enc[h][n]) — one-time transpose+convert, 4MB.
// grid (16,16), block 256, 64x64 tiles via LDS.
// ---------------------------------------------------------------------------
__global__ __launch_bounds__(256) void k_wt(
    const float* __restrict__ W, unsigned short* __restrict__ WT) {
  __shared__ float ts[64][65];
  const int hy = blockIdx.y * 64, nx = blockIdx.x * 64;
  const int tid = threadIdx.x;
#pragma unroll
  for (int i = 0; i < 16; ++i) {
    int idx = tid + i * 256, r = idx >> 6, c = idx & 63;
    ts[r][c] = W[(HIDDEN + hy + r) * HIDDEN + nx + c];
  }
  __syncthreads();
#pragma unroll
  for (int i = 0; i < 16; ++i) {
    int idx = tid + i * 256, rn = idx >> 6, ch = idx & 63;
    WT[(nx + rn) * HIDDEN + hy + ch] = f2bf(ts[ch][rn]);
  }
}

// ---------------------------------------------------------------------------
// Kernel 1: dec_proj[b][k] = dh[b] @ W_dec[:,k] + bias[k]  (fp32, tiny)
// ---------------------------------------------------------------------------
__global__ __launch_bounds__(256) void k_dec_proj(
    const float* __restrict__ dh, const float* __restrict__ W,
    const float* __restrict__ bias, float* __restrict__ out) {
  int k = blockIdx.x * 256 + threadIdx.x;
  int b0 = blockIdx.y * 4;
  __shared__ float dh_s[4][64];
  float acc[4] = {0.f, 0.f, 0.f, 0.f};
  for (int h0 = 0; h0 < HIDDEN; h0 += 64) {
    __syncthreads();
    {
      int b = threadIdx.x >> 6, hh = threadIdx.x & 63;
      dh_s[b][hh] = dh[(b0 + b) * HIDDEN + h0 + hh];
    }
    __syncthreads();
#pragma unroll 16
    for (int hh = 0; hh < 64; ++hh) {
      float w = W[(h0 + hh) * HIDDEN + k];
#pragma unroll
      for (int b = 0; b < 4; ++b) acc[b] += dh_s[b][hh] * w;
    }
  }
  float bk = bias[k];
#pragma unroll
  for (int b = 0; b < 4; ++b) out[(b0 + b) * HIDDEN + k] = acc[b] + bk;
}

// ---------------------------------------------------------------------------
// Kernel 2 (dominant): MFMA bf16 GEMM (enc @ W_enc) fused with
// tanh + v_w dot reduce. Tile 256(M rows) x 256(N kcols), BK=32, 8 waves.
// part[colblk][row] = sum_{k in colblk} tanh(dec_proj[b][k]+encproj)*v_w[k]
// ---------------------------------------------------------------------------
#define BM 256
#define BN 256
#define BK 32

__global__ __launch_bounds__(512, 2) void k_energy_mfma(
    const float* __restrict__ enc, const unsigned short* __restrict__ WT,
    const float* __restrict__ dec_proj, const float* __restrict__ v_w,
    float* __restrict__ part) {
  __shared__ unsigned short As[BM * BK];  // rows of 64B, XOR-swizzled
  __shared__ unsigned short Bs[BN * BK];
  __shared__ float red[4][BM];

  const int tid = threadIdx.x;
  const int lane = tid & 63;
  const int wid = tid >> 6;    // 0..7
  const int wm = wid >> 2;     // 0..1  (row half)
  const int wn = wid & 3;      // 0..3  (col quarter)
  const int n0 = blockIdx.x * BN;
  const int row0 = blockIdx.y * BM;
  const int b = row0 >> 11;    // row0 / SRC_LEN
  const int l16 = lane & 15;
  const int kg = lane >> 4;    // 0..3

  f32x4 acc[8][4];
#pragma unroll
  for (int m = 0; m < 8; ++m)
#pragma unroll
    for (int n = 0; n < 4; ++n) acc[m][n] = (f32x4){0.f, 0.f, 0.f, 0.f};

  const float4* enc4 = (const float4*)enc;
  const uint2* WT2 = (const uint2*)WT;  // 8B = 4 bf16

  for (int h0 = 0; h0 < HIDDEN; h0 += BK) {
    __syncthreads();
    // stage A: 256 rows x 32 h (fp32 -> bf16 on the fly). 2048 float4 chunks.
#pragma unroll
    for (int i = 0; i < 4; ++i) {
      int idx = tid + i * 512;
      int r = idx >> 3, h4 = idx & 7;
      float4 a = enc4[(size_t)(row0 + r) * 256 + (h0 >> 2) + h4];
      uint2 u;
      u.x = pack2(a.x, a.y);
      u.y = pack2(a.z, a.w);
      int off = r * 64 + ((h4 * 8) ^ ((r & 3) << 4));
      *(uint2*)((char*)As + off) = u;
    }
    // stage B: 256 n-rows x 32 h from WT (already bf16). 2048 8B chunks.
#pragma unroll
    for (int i = 0; i < 4; ++i) {
      int idx = tid + i * 512;
      int nr = idx >> 3, h8 = idx & 7;
      uint2 wv = WT2[(size_t)(n0 + nr) * 256 + (h0 >> 2) + h8];
      int off = nr * 64 + ((h8 * 8) ^ ((nr & 3) << 4));
      *(uint2*)((char*)Bs + off) = wv;
    }
    __syncthreads();

    bf16x8 afrag[8], bfrag[4];
#pragma unroll
    for (int m = 0; m < 8; ++m) {
      int r = wm * 128 + m * 16 + l16;
      int off = r * 64 + ((kg * 16) ^ ((r & 3) << 4));
      afrag[m] = *(const bf16x8*)((const char*)As + off);
    }
#pragma unroll
    for (int n = 0; n < 4; ++n) {
      int c = wn * 64 + n * 16 + l16;
      int off = c * 64 + ((kg * 16) ^ ((c & 3) << 4));
      bfrag[n] = *(const bf16x8*)((const char*)Bs + off);
    }
#pragma unroll
    for (int m = 0; m < 8; ++m)
#pragma unroll
      for (int n = 0; n < 4; ++n)
        acc[m][n] = __builtin_amdgcn_mfma_f32_16x16x32_bf16(
            afrag[m], bfrag[n], acc[m][n], 0, 0, 0);
  }

  // epilogue: tanh + v_w dot; C/D layout: col=l16, row=kg*4+reg (m89-verified)
  float dv[4], vv[4];
#pragma unroll
  for (int n = 0; n < 4; ++n) {
    int kc = n0 + wn * 64 + n * 16 + l16;
    dv[n] = dec_proj[b * HIDDEN + kc];
    vv[n] = v_w[kc];
  }
#pragma unroll
  for (int m = 0; m < 8; ++m) {
#pragma unroll
    for (int r = 0; r < 4; ++r) {
      float p = 0.f;
#pragma unroll
      for (int n = 0; n < 4; ++n) {
        float x = dv[n] + acc[m][n][r];
        float t = 1.f - 2.f / (__expf(2.f * x) + 1.f);  // tanh, saturating
        p += t * vv[n];
      }
      p += __shfl_xor(p, 1);
      p += __shfl_xor(p, 2);
      p += __shfl_xor(p, 4);
      p += __shfl_xor(p, 8);
      if (l16 == 0) red[wn][wm * 128 + m * 16 + kg * 4 + r] = p;
    }
  }
  __syncthreads();
  if (tid < BM) {
    float s = red[0][tid] + red[1][tid] + red[2][tid] + red[3][tid];
    part[(size_t)blockIdx.x * NROWS + row0 + tid] = s;
  }
}

// ---------------------------------------------------------------------------
// Kernel 3: sum 4 col-block partials + masked softmax. grid 32, block 256.
// ---------------------------------------------------------------------------
__global__ __launch_bounds__(256) void k_softmax(
    const float* __restrict__ part, const int* __restrict__ mask,
    float* __restrict__ out_w) {
  int b = blockIdx.x, tid = threadIdx.x;
  __shared__ float red[4], red2[4];
  float l[8];
  float m = -INFINITY;
#pragma unroll
  for (int j = 0; j < 8; ++j) {
    int s = tid + 256 * j;
    int row = b * SRC_LEN + s;
    float x = part[row] + part[NROWS + row] + part[2 * NROWS + row] +
              part[3 * NROWS + row];
    l[j] = (mask[row] == 0) ? NEG_BIG : x;
    m = fmaxf(m, l[j]);
  }
#pragma unroll
  for (int off = 32; off; off >>= 1) m = fmaxf(m, __shfl_xor(m, off));
  if ((tid & 63) == 0) red[tid >> 6] = m;
  __syncthreads();
  m = fmaxf(fmaxf(red[0], red[1]), fmaxf(red[2], red[3]));
  float sum = 0.f;
#pragma unroll
  for (int j = 0; j < 8; ++j) {
    l[j] = expf(l[j] - m);
    sum += l[j];
  }
#pragma unroll
  for (int off = 32; off; off >>= 1) sum += __shfl_xor(sum, off);
  if ((tid & 63) == 0) red2[tid >> 6] = sum;
  __syncthreads();
  sum = red2[0] + red2[1] + red2[2] + red2[3];
  float inv = 1.f / sum;
#pragma unroll
  for (int j = 0; j < 8; ++j) out_w[b * SRC_LEN + tid + 256 * j] = l[j] * inv;
}

// ---------------------------------------------------------------------------
// Kernel 4: context partials. grid (32,16), block 256.
// ---------------------------------------------------------------------------
__global__ __launch_bounds__(256) void k_ctx_partial(
    const float* __restrict__ w, const float* __restrict__ enc,
    float* __restrict__ part) {
  int b = blockIdx.x, sg = blockIdx.y, tid = threadIdx.x;
  const float4* enc4 = (const float4*)enc;
  float4 acc = {0.f, 0.f, 0.f, 0.f};
  int s0 = sg * 128;
#pragma unroll 4
  for (int s = 0; s < 128; ++s) {
    float ws = w[b * SRC_LEN + s0 + s];
    float4 e = enc4[(size_t)(b * SRC_LEN + s0 + s) * 256 + tid];
    acc.x += ws * e.x;
    acc.y += ws * e.y;
    acc.z += ws * e.z;
    acc.w += ws * e.w;
  }
  ((float4*)part)[(b * 16 + sg) * 256 + tid] = acc;
}

// ---------------------------------------------------------------------------
// Kernel 5: reduce 16 partials -> context. grid 32, block 256.
// ---------------------------------------------------------------------------
__global__ __launch_bounds__(256) void k_ctx_reduce(
    const float* __restrict__ part, float* __restrict__ ctx) {
  int b = blockIdx.x, tid = threadIdx.x;
  float4 acc = {0.f, 0.f, 0.f, 0.f};
#pragma unroll
  for (int sg = 0; sg < 16; ++sg) {
    float4 p = ((const float4*)part)[(b * 16 + sg) * 256 + tid];
    acc.x += p.x;
    acc.y += p.y;
    acc.z += p.z;
    acc.w += p.w;
  }
  ((float4*)ctx)[b * 256 + tid] = acc;
}

// ---------------------------------------------------------------------------
extern "C" void kernel_launch(void* const* d_in, const int* in_sizes, int n_in,
                              void* d_out, int out_size, void* d_ws, size_t ws_size,
                              hipStream_t stream) {
  const float* dh = (const float*)d_in[0];        // [32][1024]
  const float* enc = (const float*)d_in[1];       // [32][2048][1024]
  const int* mask = (const int*)d_in[2];          // [32][2048]
  const float* attn_W = (const float*)d_in[3];    // [2048][1024]
  const float* attn_b = (const float*)d_in[4];    // [1024]
  const float* v_w = (const float*)d_in[5];       // [1024]

  float* out_w = (float*)d_out;                   // [32][2048]
  float* out_ctx = (float*)d_out + NROWS;         // [32][1024]

  float* ws = (float*)d_ws;
  float* part = ws;                               // 4 * 65536
  float* dec_proj = ws + 4 * NROWS;               // 32768
  float* ctxpart = dec_proj + BATCH * HIDDEN;     // 524288
  unsigned short* WT = (unsigned short*)(ctxpart + BATCH * 16 * HIDDEN);  // 1Mi bf16

  k_wt<<<dim3(16, 16), 256, 0, stream>>>(attn_W, WT);
  k_dec_proj<<<dim3(4, 8), 256, 0, stream>>>(dh, attn_W, attn_b, dec_proj);
  k_energy_mfma<<<dim3(4, 256), 512, 0, stream>>>(enc, WT, dec_proj, v_w, part);
  k_softmax<<<dim3(BATCH), 256, 0, stream>>>(part, mask, out_w);
  k_ctx_partial<<<dim3(BATCH, 16), 256, 0, stream>>>(out_w, enc, ctxpart);
  k_ctx_reduce<<<dim3(BATCH), 256, 0, stream>>>(ctxpart, out_ctx);
}

// Round 3
// 340.413 us; speedup vs baseline: 8.9819x; 2.1223x over previous
//
#include <hip/hip_runtime.h>
#include <hip/hip_bf16.h>
#include <math.h>

#define HIDDEN 1024
#define BATCH 32
#define SRC_LEN 2048
#define NROWS (BATCH * SRC_LEN)   // 65536
#define NEG_BIG -10000000000.0f

typedef __attribute__((ext_vector_type(8))) short bf16x8;
typedef __attribute__((ext_vector_type(4))) float f32x4;

static __device__ __forceinline__ unsigned short f2bf(float f) {
  unsigned u = __float_as_uint(f);
  u = u + 0x7fffu + ((u >> 16) & 1u);
  return (unsigned short)(u >> 16);
}
static __device__ __forceinline__ unsigned pack2(float a, float b) {
  return (unsigned)f2bf(a) | ((unsigned)f2bf(b) << 16);
}

// ---------------------------------------------------------------------------
// Kernel 0: WT[n][h] = bf16(W_enc[h][n]) — one-time transpose+convert.
// ---------------------------------------------------------------------------
__global__ __launch_bounds__(256) void k_wt(
    const float* __restrict__ W, unsigned short* __restrict__ WT) {
  __shared__ float ts[64][65];
  const int hy = blockIdx.y * 64, nx = blockIdx.x * 64;
  const int tid = threadIdx.x;
#pragma unroll
  for (int i = 0; i < 16; ++i) {
    int idx = tid + i * 256, r = idx >> 6, c = idx & 63;
    ts[r][c] = W[(HIDDEN + hy + r) * HIDDEN + nx + c];
  }
  __syncthreads();
#pragma unroll
  for (int i = 0; i < 16; ++i) {
    int idx = tid + i * 256, rn = idx >> 6, ch = idx & 63;
    WT[(nx + rn) * HIDDEN + hy + ch] = f2bf(ts[ch][rn]);
  }
}

// ---------------------------------------------------------------------------
// Kernel 1a: dec partials. grid (16 ktiles, 16 hchunks), block 256.
// decpart[hc][b][k] = sum_{h in hc*64..} dh[b][h] * W_dec[h][k]
// ---------------------------------------------------------------------------
__global__ __launch_bounds__(256) void k_dec_part(
    const float* __restrict__ dh, const float* __restrict__ W,
    float* __restrict__ decpart) {
  const int kl = threadIdx.x & 63;
  const int bq = threadIdx.x >> 6;  // 0..3 -> batches bq*8..bq*8+7
  const int k = blockIdx.x * 64 + kl;
  const int h0 = blockIdx.y * 64;
  __shared__ float dh_s[64][33];  // [h][b], padded (+1 breaks 32-stride)
#pragma unroll
  for (int i = 0; i < 8; ++i) {
    int idx = threadIdx.x + i * 256;  // 0..2047
    int b = idx >> 6, hh = idx & 63;
    dh_s[hh][b] = dh[b * HIDDEN + h0 + hh];
  }
  __syncthreads();
  float acc[8] = {0.f, 0.f, 0.f, 0.f, 0.f, 0.f, 0.f, 0.f};
#pragma unroll
  for (int hh = 0; hh < 64; ++hh) {
    float w = W[(h0 + hh) * HIDDEN + k];
#pragma unroll
    for (int bb = 0; bb < 8; ++bb) acc[bb] += dh_s[hh][bq * 8 + bb] * w;
  }
#pragma unroll
  for (int bb = 0; bb < 8; ++bb)
    decpart[blockIdx.y * (BATCH * HIDDEN) + (bq * 8 + bb) * HIDDEN + k] = acc[bb];
}

// ---------------------------------------------------------------------------
// Kernel 1b: reduce 16 h-chunk partials + bias. grid 128, block 256.
// ---------------------------------------------------------------------------
__global__ __launch_bounds__(256) void k_dec_reduce(
    const float* __restrict__ decpart, const float* __restrict__ bias,
    float* __restrict__ out) {
  int e = blockIdx.x * 256 + threadIdx.x;  // 0..32767
  float s = bias[e & (HIDDEN - 1)];
#pragma unroll
  for (int hc = 0; hc < 16; ++hc) s += decpart[hc * (BATCH * HIDDEN) + e];
  out[e] = s;
}

// ---------------------------------------------------------------------------
// Kernel 2 (dominant): MFMA bf16 GEMM (enc @ W_enc) fused with
// tanh + v_w dot reduce. Tile 256(M rows) x 256(N kcols), BK=32, 8 waves.
// ---------------------------------------------------------------------------
#define BM 256
#define BN 256
#define BK 32

__global__ __launch_bounds__(512, 2) void k_energy_mfma(
    const float* __restrict__ enc, const unsigned short* __restrict__ WT,
    const float* __restrict__ dec_proj, const float* __restrict__ v_w,
    float* __restrict__ part) {
  __shared__ unsigned short As[BM * BK];  // rows of 64B, XOR-swizzled
  __shared__ unsigned short Bs[BN * BK];
  __shared__ float red[4][BM];

  const int tid = threadIdx.x;
  const int lane = tid & 63;
  const int wid = tid >> 6;    // 0..7
  const int wm = wid >> 2;     // 0..1  (row half)
  const int wn = wid & 3;      // 0..3  (col quarter)
  const int n0 = blockIdx.x * BN;
  const int row0 = blockIdx.y * BM;
  const int b = row0 >> 11;    // row0 / SRC_LEN
  const int l16 = lane & 15;
  const int kg = lane >> 4;    // 0..3

  f32x4 acc[8][4];
#pragma unroll
  for (int m = 0; m < 8; ++m)
#pragma unroll
    for (int n = 0; n < 4; ++n) acc[m][n] = (f32x4){0.f, 0.f, 0.f, 0.f};

  const float4* enc4 = (const float4*)enc;
  const uint2* WT2 = (const uint2*)WT;  // 8B = 4 bf16

  for (int h0 = 0; h0 < HIDDEN; h0 += BK) {
    __syncthreads();
    // stage A: 256 rows x 32 h (fp32 -> bf16 on the fly)
#pragma unroll
    for (int i = 0; i < 4; ++i) {
      int idx = tid + i * 512;
      int r = idx >> 3, h4 = idx & 7;
      float4 a = enc4[(size_t)(row0 + r) * 256 + (h0 >> 2) + h4];
      uint2 u;
      u.x = pack2(a.x, a.y);
      u.y = pack2(a.z, a.w);
      int off = r * 64 + ((h4 * 8) ^ ((r & 3) << 4));
      *(uint2*)((char*)As + off) = u;
    }
    // stage B: 256 n-rows x 32 h from WT (already bf16)
#pragma unroll
    for (int i = 0; i < 4; ++i) {
      int idx = tid + i * 512;
      int nr = idx >> 3, h8 = idx & 7;
      uint2 wv = WT2[(size_t)(n0 + nr) * 256 + (h0 >> 2) + h8];
      int off = nr * 64 + ((h8 * 8) ^ ((nr & 3) << 4));
      *(uint2*)((char*)Bs + off) = wv;
    }
    __syncthreads();

    bf16x8 afrag[8], bfrag[4];
#pragma unroll
    for (int m = 0; m < 8; ++m) {
      int r = wm * 128 + m * 16 + l16;
      int off = r * 64 + ((kg * 16) ^ ((r & 3) << 4));
      afrag[m] = *(const bf16x8*)((const char*)As + off);
    }
#pragma unroll
    for (int n = 0; n < 4; ++n) {
      int c = wn * 64 + n * 16 + l16;
      int off = c * 64 + ((kg * 16) ^ ((c & 3) << 4));
      bfrag[n] = *(const bf16x8*)((const char*)Bs + off);
    }
#pragma unroll
    for (int m = 0; m < 8; ++m)
#pragma unroll
      for (int n = 0; n < 4; ++n)
        acc[m][n] = __builtin_amdgcn_mfma_f32_16x16x32_bf16(
            afrag[m], bfrag[n], acc[m][n], 0, 0, 0);
  }

  // epilogue: tanh + v_w dot; C/D layout: col=l16, row=kg*4+reg
  float dv[4], vv[4];
#pragma unroll
  for (int n = 0; n < 4; ++n) {
    int kc = n0 + wn * 64 + n * 16 + l16;
    dv[n] = dec_proj[b * HIDDEN + kc];
    vv[n] = v_w[kc];
  }
#pragma unroll
  for (int m = 0; m < 8; ++m) {
#pragma unroll
    for (int r = 0; r < 4; ++r) {
      float p = 0.f;
#pragma unroll
      for (int n = 0; n < 4; ++n) {
        float x = dv[n] + acc[m][n][r];
        float t = 1.f - 2.f / (__expf(2.f * x) + 1.f);  // tanh, saturating
        p += t * vv[n];
      }
      p += __shfl_xor(p, 1);
      p += __shfl_xor(p, 2);
      p += __shfl_xor(p, 4);
      p += __shfl_xor(p, 8);
      if (l16 == 0) red[wn][wm * 128 + m * 16 + kg * 4 + r] = p;
    }
  }
  __syncthreads();
  if (tid < BM) {
    float s = red[0][tid] + red[1][tid] + red[2][tid] + red[3][tid];
    part[(size_t)blockIdx.x * NROWS + row0 + tid] = s;
  }
}

// ---------------------------------------------------------------------------
// Kernel 3: sum 4 col-block partials + masked softmax. grid 32, block 256.
// ---------------------------------------------------------------------------
__global__ __launch_bounds__(256) void k_softmax(
    const float* __restrict__ part, const int* __restrict__ mask,
    float* __restrict__ out_w) {
  int b = blockIdx.x, tid = threadIdx.x;
  __shared__ float red[4], red2[4];
  float l[8];
  float m = -INFINITY;
#pragma unroll
  for (int j = 0; j < 8; ++j) {
    int s = tid + 256 * j;
    int row = b * SRC_LEN + s;
    float x = part[row] + part[NROWS + row] + part[2 * NROWS + row] +
              part[3 * NROWS + row];
    l[j] = (mask[row] == 0) ? NEG_BIG : x;
    m = fmaxf(m, l[j]);
  }
#pragma unroll
  for (int off = 32; off; off >>= 1) m = fmaxf(m, __shfl_xor(m, off));
  if ((tid & 63) == 0) red[tid >> 6] = m;
  __syncthreads();
  m = fmaxf(fmaxf(red[0], red[1]), fmaxf(red[2], red[3]));
  float sum = 0.f;
#pragma unroll
  for (int j = 0; j < 8; ++j) {
    l[j] = expf(l[j] - m);
    sum += l[j];
  }
#pragma unroll
  for (int off = 32; off; off >>= 1) sum += __shfl_xor(sum, off);
  if ((tid & 63) == 0) red2[tid >> 6] = sum;
  __syncthreads();
  sum = red2[0] + red2[1] + red2[2] + red2[3];
  float inv = 1.f / sum;
#pragma unroll
  for (int j = 0; j < 8; ++j) out_w[b * SRC_LEN + tid + 256 * j] = l[j] * inv;
}

// ---------------------------------------------------------------------------
// Kernel 4: context partials. grid (32,16), block 256.
// ---------------------------------------------------------------------------
__global__ __launch_bounds__(256) void k_ctx_partial(
    const float* __restrict__ w, const float* __restrict__ enc,
    float* __restrict__ part) {
  int b = blockIdx.x, sg = blockIdx.y, tid = threadIdx.x;
  const float4* enc4 = (const float4*)enc;
  float4 acc = {0.f, 0.f, 0.f, 0.f};
  int s0 = sg * 128;
#pragma unroll 4
  for (int s = 0; s < 128; ++s) {
    float ws = w[b * SRC_LEN + s0 + s];
    float4 e = enc4[(size_t)(b * SRC_LEN + s0 + s) * 256 + tid];
    acc.x += ws * e.x;
    acc.y += ws * e.y;
    acc.z += ws * e.z;
    acc.w += ws * e.w;
  }
  ((float4*)part)[(b * 16 + sg) * 256 + tid] = acc;
}

// ---------------------------------------------------------------------------
// Kernel 5: reduce 16 partials -> context. grid 32, block 256.
// ---------------------------------------------------------------------------
__global__ __launch_bounds__(256) void k_ctx_reduce(
    const float* __restrict__ part, float* __restrict__ ctx) {
  int b = blockIdx.x, tid = threadIdx.x;
  float4 acc = {0.f, 0.f, 0.f, 0.f};
#pragma unroll
  for (int sg = 0; sg < 16; ++sg) {
    float4 p = ((const float4*)part)[(b * 16 + sg) * 256 + tid];
    acc.x += p.x;
    acc.y += p.y;
    acc.z += p.z;
    acc.w += p.w;
  }
  ((float4*)ctx)[b * 256 + tid] = acc;
}

// ---------------------------------------------------------------------------
extern "C" void kernel_launch(void* const* d_in, const int* in_sizes, int n_in,
                              void* d_out, int out_size, void* d_ws, size_t ws_size,
                              hipStream_t stream) {
  const float* dh = (const float*)d_in[0];        // [32][1024]
  const float* enc = (const float*)d_in[1];       // [32][2048][1024]
  const int* mask = (const int*)d_in[2];          // [32][2048]
  const float* attn_W = (const float*)d_in[3];    // [2048][1024]
  const float* attn_b = (const float*)d_in[4];    // [1024]
  const float* v_w = (const float*)d_in[5];       // [1024]

  float* out_w = (float*)d_out;                   // [32][2048]
  float* out_ctx = (float*)d_out + NROWS;         // [32][1024]

  float* ws = (float*)d_ws;
  float* part = ws;                               // 4 * 65536
  float* dec_proj = ws + 4 * NROWS;               // 32768
  float* ctxpart = dec_proj + BATCH * HIDDEN;     // 32*16*1024 = 524288
  float* decpart = ctxpart + BATCH * 16 * HIDDEN; // 16*32*1024 = 524288
  unsigned short* WT = (unsigned short*)(decpart + 16 * BATCH * HIDDEN);  // 1Mi bf16

  k_wt<<<dim3(16, 16), 256, 0, stream>>>(attn_W, WT);
  k_dec_part<<<dim3(16, 16), 256, 0, stream>>>(dh, attn_W, decpart);
  k_dec_reduce<<<dim3(128), 256, 0, stream>>>(decpart, attn_b, dec_proj);
  k_energy_mfma<<<dim3(4, 256), 512, 0, stream>>>(enc, WT, dec_proj, v_w, part);
  k_softmax<<<dim3(BATCH), 256, 0, stream>>>(part, mask, out_w);
  k_ctx_partial<<<dim3(BATCH, 16), 256, 0, stream>>>(out_w, enc, ctxpart);
  k_ctx_reduce<<<dim3(BATCH), 256, 0, stream>>>(ctxpart, out_ctx);
}

// Round 5
// 272.320 us; speedup vs baseline: 11.2278x; 1.2500x over previous
//
#include <hip/hip_runtime.h>
#include <hip/hip_bf16.h>
#include <math.h>

#define HIDDEN 1024
#define BATCH 32
#define SRC_LEN 2048
#define NROWS (BATCH * SRC_LEN)   // 65536
#define NEG_BIG -10000000000.0f

typedef __attribute__((ext_vector_type(8))) short bf16x8;
typedef __attribute__((ext_vector_type(4))) float f32x4;
typedef __attribute__((ext_vector_type(4))) unsigned uint32x4;

static __device__ __forceinline__ unsigned short f2bf(float f) {
  unsigned u = __float_as_uint(f);
  u = u + 0x7fffu + ((u >> 16) & 1u);
  return (unsigned short)(u >> 16);
}
static __device__ __forceinline__ unsigned pack2(float a, float b) {
  return (unsigned)f2bf(a) | ((unsigned)f2bf(b) << 16);
}

// ---------------------------------------------------------------------------
// Kernel 0: WT[n][h] = bf16(W_enc[h][n]) — one-time transpose+convert.
// ---------------------------------------------------------------------------
__global__ __launch_bounds__(256) void k_wt(
    const float* __restrict__ W, unsigned short* __restrict__ WT) {
  __shared__ float ts[64][65];
  const int hy = blockIdx.y * 64, nx = blockIdx.x * 64;
  const int tid = threadIdx.x;
#pragma unroll
  for (int i = 0; i < 16; ++i) {
    int idx = tid + i * 256, r = idx >> 6, c = idx & 63;
    ts[r][c] = W[(HIDDEN + hy + r) * HIDDEN + nx + c];
  }
  __syncthreads();
#pragma unroll
  for (int i = 0; i < 16; ++i) {
    int idx = tid + i * 256, rn = idx >> 6, ch = idx & 63;
    WT[(nx + rn) * HIDDEN + hy + ch] = f2bf(ts[ch][rn]);
  }
}

// ---------------------------------------------------------------------------
// Kernel 1a: dec partials. grid (16 ktiles, 16 hchunks), block 256.
// ---------------------------------------------------------------------------
__global__ __launch_bounds__(256) void k_dec_part(
    const float* __restrict__ dh, const float* __restrict__ W,
    float* __restrict__ decpart) {
  const int kl = threadIdx.x & 63;
  const int bq = threadIdx.x >> 6;
  const int k = blockIdx.x * 64 + kl;
  const int h0 = blockIdx.y * 64;
  __shared__ float dh_s[64][33];
#pragma unroll
  for (int i = 0; i < 8; ++i) {
    int idx = threadIdx.x + i * 256;
    int b = idx >> 6, hh = idx & 63;
    dh_s[hh][b] = dh[b * HIDDEN + h0 + hh];
  }
  __syncthreads();
  float acc[8] = {0.f, 0.f, 0.f, 0.f, 0.f, 0.f, 0.f, 0.f};
#pragma unroll
  for (int hh = 0; hh < 64; ++hh) {
    float w = W[(h0 + hh) * HIDDEN + k];
#pragma unroll
    for (int bb = 0; bb < 8; ++bb) acc[bb] += dh_s[hh][bq * 8 + bb] * w;
  }
#pragma unroll
  for (int bb = 0; bb < 8; ++bb)
    decpart[blockIdx.y * (BATCH * HIDDEN) + (bq * 8 + bb) * HIDDEN + k] = acc[bb];
}

__global__ __launch_bounds__(256) void k_dec_reduce(
    const float* __restrict__ decpart, const float* __restrict__ bias,
    float* __restrict__ out) {
  int e = blockIdx.x * 256 + threadIdx.x;
  float s = bias[e & (HIDDEN - 1)];
#pragma unroll
  for (int hc = 0; hc < 16; ++hc) s += decpart[hc * (BATCH * HIDDEN) + e];
  out[e] = s;
}

// ---------------------------------------------------------------------------
// Kernel 2 (dominant): pipelined MFMA bf16 GEMM fused with tanh + v_w dot.
// BM=128 (M rows) x BN=256 (N kcols), BK=64, 8 waves (2M x 4N), LDS dbuf.
// Schedule per K-step: issue loads(t+1) -> MFMA(t) -> write LDS(t+1) -> bar.
// ---------------------------------------------------------------------------
#define BM 128
#define BN 256
#define BK 64
#define NT (HIDDEN / BK)   // 16

__global__ __launch_bounds__(512, 2) void k_energy_mfma(
    const float* __restrict__ enc, const unsigned short* __restrict__ WT,
    const float* __restrict__ dec_proj, const float* __restrict__ v_w,
    float* __restrict__ part) {
  __shared__ unsigned short As[2][BM * BK];  // 2 x 16 KB, 128B rows, swizzled
  __shared__ unsigned short Bs[2][BN * BK];  // 2 x 32 KB
  __shared__ float red[4][BM];

  const int tid = threadIdx.x;
  const int lane = tid & 63;
  const int wid = tid >> 6;    // 0..7
  const int wm = wid >> 2;     // 0..1  (row half of 128)
  const int wn = wid & 3;      // 0..3  (col quarter of 256)
  const int l16 = lane & 15;
  const int kg = lane >> 4;    // 0..3

  // XCD-aware bijective swizzle: nwg=2048, 256 logical blocks per XCD chunk.
  const int bid = blockIdx.x;
  const int l = (bid & 7) * 256 + (bid >> 3);
  const int n0 = (l & 3) * BN;
  const int row0 = (l >> 2) * BM;
  const int b = row0 >> 11;

  f32x4 acc[4][4];
#pragma unroll
  for (int m = 0; m < 4; ++m)
#pragma unroll
    for (int n = 0; n < 4; ++n) acc[m][n] = (f32x4){0.f, 0.f, 0.f, 0.f};

  const float4* enc4 = (const float4*)enc;
  const uint32x4* WT4 = (const uint32x4*)WT;  // 16B = 8 bf16; row = 128 uint4

  float4 pa[4];
  uint32x4 pb[4];

#define LOADAB(t)                                                         \
  do {                                                                    \
    int h0 = (t) * BK;                                                    \
    _Pragma("unroll") for (int i = 0; i < 4; ++i) {                       \
      int chunk = tid + i * 512;                                          \
      int r = chunk >> 4, c4 = chunk & 15;                                \
      pa[i] = enc4[(size_t)(row0 + r) * 256 + (h0 >> 2) + c4];            \
    }                                                                     \
    _Pragma("unroll") for (int i = 0; i < 4; ++i) {                       \
      int chunk = tid + i * 512;                                          \
      int nr = chunk >> 3, c16 = chunk & 7;                               \
      pb[i] = WT4[(size_t)(n0 + nr) * 128 + (h0 >> 3) + c16];             \
    }                                                                     \
  } while (0)

#define STOREAB(bufi)                                                     \
  do {                                                                    \
    _Pragma("unroll") for (int i = 0; i < 4; ++i) {                       \
      int chunk = tid + i * 512;                                          \
      int r = chunk >> 4, c4 = chunk & 15;                                \
      unsigned off = r * 128 + ((c4 * 8) ^ ((r & 7) << 4));               \
      uint2 u;                                                            \
      u.x = pack2(pa[i].x, pa[i].y);                                      \
      u.y = pack2(pa[i].z, pa[i].w);                                      \
      *(uint2*)((char*)As[bufi] + off) = u;                               \
    }                                                                     \
    _Pragma("unroll") for (int i = 0; i < 4; ++i) {                       \
      int chunk = tid + i * 512;                                          \
      int nr = chunk >> 3, c16 = chunk & 7;                               \
      unsigned off = nr * 128 + ((c16 * 16) ^ ((nr & 7) << 4));           \
      *(uint32x4*)((char*)Bs[bufi] + off) = pb[i];                        \
    }                                                                     \
  } while (0)

  LOADAB(0);
  STOREAB(0);
  __syncthreads();

  for (int t = 0; t < NT; ++t) {
    const int cur = t & 1;
    if (t + 1 < NT) LOADAB(t + 1);  // issue early — hides under MFMA

    __builtin_amdgcn_s_setprio(1);
#pragma unroll
    for (int ks = 0; ks < 2; ++ks) {
      bf16x8 af[4], bv[4];
#pragma unroll
      for (int m = 0; m < 4; ++m) {
        int r = wm * 64 + m * 16 + l16;
        unsigned off = r * 128 + ((ks * 64 + kg * 16) ^ ((r & 7) << 4));
        af[m] = *(const bf16x8*)((const char*)As[cur] + off);
      }
#pragma unroll
      for (int n = 0; n < 4; ++n) {
        int c = wn * 64 + n * 16 + l16;
        unsigned off = c * 128 + ((ks * 64 + kg * 16) ^ ((c & 7) << 4));
        bv[n] = *(const bf16x8*)((const char*)Bs[cur] + off);
      }
#pragma unroll
      for (int m = 0; m < 4; ++m)
#pragma unroll
        for (int n = 0; n < 4; ++n)
          acc[m][n] = __builtin_amdgcn_mfma_f32_16x16x32_bf16(
              af[m], bv[n], acc[m][n], 0, 0, 0);
    }
    __builtin_amdgcn_s_setprio(0);

    if (t + 1 < NT) STOREAB(cur ^ 1);  // write-late (vmcnt inserted here)
    __syncthreads();
  }

  // epilogue: tanh + v_w dot; C/D layout: col=l16, row=kg*4+reg
  float dv[4], vv[4];
#pragma unroll
  for (int n = 0; n < 4; ++n) {
    int kc = n0 + wn * 64 + n * 16 + l16;
    dv[n] = dec_proj[b * HIDDEN + kc];
    vv[n] = v_w[kc];
  }
#pragma unroll
  for (int m = 0; m < 4; ++m) {
#pragma unroll
    for (int r = 0; r < 4; ++r) {
      float p = 0.f;
#pragma unroll
      for (int n = 0; n < 4; ++n) {
        float x = dv[n] + acc[m][n][r];
        float t = 1.f - 2.f / (__expf(2.f * x) + 1.f);  // tanh, saturating
        p += t * vv[n];
      }
      p += __shfl_xor(p, 1);
      p += __shfl_xor(p, 2);
      p += __shfl_xor(p, 4);
      p += __shfl_xor(p, 8);
      if (l16 == 0) red[wn][wm * 64 + m * 16 + kg * 4 + r] = p;
    }
  }
  __syncthreads();
  if (tid < BM) {
    float s = red[0][tid] + red[1][tid] + red[2][tid] + red[3][tid];
    part[(size_t)(l & 3) * NROWS + row0 + tid] = s;
  }
#undef LOADAB
#undef STOREAB
}

// ---------------------------------------------------------------------------
// Kernel 3: sum 4 col-block partials + masked softmax. grid 32, block 256.
// ---------------------------------------------------------------------------
__global__ __launch_bounds__(256) void k_softmax(
    const float* __restrict__ part, const int* __restrict__ mask,
    float* __restrict__ out_w) {
  int b = blockIdx.x, tid = threadIdx.x;
  __shared__ float red[4], red2[4];
  float l[8];
  float m = -INFINITY;
#pragma unroll
  for (int j = 0; j < 8; ++j) {
    int s = tid + 256 * j;
    int row = b * SRC_LEN + s;
    float x = part[row] + part[NROWS + row] + part[2 * NROWS + row] +
              part[3 * NROWS + row];
    l[j] = (mask[row] == 0) ? NEG_BIG : x;
    m = fmaxf(m, l[j]);
  }
#pragma unroll
  for (int off = 32; off; off >>= 1) m = fmaxf(m, __shfl_xor(m, off));
  if ((tid & 63) == 0) red[tid >> 6] = m;
  __syncthreads();
  m = fmaxf(fmaxf(red[0], red[1]), fmaxf(red[2], red[3]));
  float sum = 0.f;
#pragma unroll
  for (int j = 0; j < 8; ++j) {
    l[j] = expf(l[j] - m);
    sum += l[j];
  }
#pragma unroll
  for (int off = 32; off; off >>= 1) sum += __shfl_xor(sum, off);
  if ((tid & 63) == 0) red2[tid >> 6] = sum;
  __syncthreads();
  sum = red2[0] + red2[1] + red2[2] + red2[3];
  float inv = 1.f / sum;
#pragma unroll
  for (int j = 0; j < 8; ++j) out_w[b * SRC_LEN + tid + 256 * j] = l[j] * inv;
}

// ---------------------------------------------------------------------------
// Kernel 4: context partials. grid (32,16), block 256.
// ---------------------------------------------------------------------------
__global__ __launch_bounds__(256) void k_ctx_partial(
    const float* __restrict__ w, const float* __restrict__ enc,
    float* __restrict__ part) {
  int b = blockIdx.x, sg = blockIdx.y, tid = threadIdx.x;
  const float4* enc4 = (const float4*)enc;
  float4 acc = {0.f, 0.f, 0.f, 0.f};
  int s0 = sg * 128;
#pragma unroll 4
  for (int s = 0; s < 128; ++s) {
    float ws = w[b * SRC_LEN + s0 + s];
    float4 e = enc4[(size_t)(b * SRC_LEN + s0 + s) * 256 + tid];
    acc.x += ws * e.x;
    acc.y += ws * e.y;
    acc.z += ws * e.z;
    acc.w += ws * e.w;
  }
  ((float4*)part)[(b * 16 + sg) * 256 + tid] = acc;
}

__global__ __launch_bounds__(256) void k_ctx_reduce(
    const float* __restrict__ part, float* __restrict__ ctx) {
  int b = blockIdx.x, tid = threadIdx.x;
  float4 acc = {0.f, 0.f, 0.f, 0.f};
#pragma unroll
  for (int sg = 0; sg < 16; ++sg) {
    float4 p = ((const float4*)part)[(b * 16 + sg) * 256 + tid];
    acc.x += p.x;
    acc.y += p.y;
    acc.z += p.z;
    acc.w += p.w;
  }
  ((float4*)ctx)[b * 256 + tid] = acc;
}

// ---------------------------------------------------------------------------
extern "C" void kernel_launch(void* const* d_in, const int* in_sizes, int n_in,
                              void* d_out, int out_size, void* d_ws, size_t ws_size,
                              hipStream_t stream) {
  const float* dh = (const float*)d_in[0];
  const float* enc = (const float*)d_in[1];
  const int* mask = (const int*)d_in[2];
  const float* attn_W = (const float*)d_in[3];
  const float* attn_b = (const float*)d_in[4];
  const float* v_w = (const float*)d_in[5];

  float* out_w = (float*)d_out;                   // [32][2048]
  float* out_ctx = (float*)d_out + NROWS;         // [32][1024]

  float* ws = (float*)d_ws;
  float* part = ws;                               // 4 * 65536
  float* dec_proj = ws + 4 * NROWS;               // 32768
  float* ctxpart = dec_proj + BATCH * HIDDEN;     // 524288
  float* decpart = ctxpart + BATCH * 16 * HIDDEN; // 524288
  unsigned short* WT = (unsigned short*)(decpart + 16 * BATCH * HIDDEN);

  k_wt<<<dim3(16, 16), 256, 0, stream>>>(attn_W, WT);
  k_dec_part<<<dim3(16, 16), 256, 0, stream>>>(dh, attn_W, decpart);
  k_dec_reduce<<<dim3(128), 256, 0, stream>>>(decpart, attn_b, dec_proj);
  k_energy_mfma<<<dim3(2048), 512, 0, stream>>>(enc, WT, dec_proj, v_w, part);
  k_softmax<<<dim3(BATCH), 256, 0, stream>>>(part, mask, out_w);
  k_ctx_partial<<<dim3(BATCH, 16), 256, 0, stream>>>(out_w, enc, ctxpart);
  k_ctx_reduce<<<dim3(BATCH), 256, 0, stream>>>(ctxpart, out_ctx);
}